// Round 3
// baseline (529.725 us; speedup 1.0000x reference)
//
#include <hip/hip_runtime.h>
#include <hip/hip_bf16.h>

// SparseFFN R6: gemm rebuilt as 8-wave 128x256xK2048 deep-pipelined schedule
// (T3+T4 counted-vmcnt phases + T5 setprio), dual-expert folded into virtual
// K = [W[e0]; W[e1]]. 4 phases/K-tile, per-phase vmcnt(5,5,6,4), peeled tail.
// sum_cvt / router2 / wcvt unchanged from R4.

#define BD 4
#define LD 4096
#define DD 1024
#define ED 64
#define CHUNKD 128
#define NBITS 6
#define NCHUNK 128   // B * L/CHUNK

typedef __bf16 bf16_8 __attribute__((ext_vector_type(8)));
typedef __bf16 bf16_4 __attribute__((ext_vector_type(4)));
typedef float floatx4 __attribute__((ext_vector_type(4)));

// Wt tile-order cell: [e][nt(8)][s(32)][rb(8)][lane(64)] x 8 bf16 (16B).
// cell(e,nt,s,rb,l) holds W[e][k = s*32 + (l>>4)*8 + j][n = nt*128 + rb*16 + (l&15)], j=0..7
#define WT_PER_ENT  131072          // 32*8*64*8 elems = 256 KB per (e,nt)

// ---------------- fused: x -> bf16 A (row-major), per-(chunk,tg) fp64 col sums
__global__ __launch_bounds__(256) void sum_cvt_kernel(
    const float* __restrict__ x, __bf16* __restrict__ a, double* __restrict__ csum_p)
{
    const int chunk = blockIdx.x >> 3;
    const int tg = blockIdx.x & 7;
    const size_t base = (size_t)chunk * CHUNKD * DD + (size_t)tg * 16 * DD;
    const float* xc = x + base;
    __bf16* ac = a + base;
    const int t = threadIdx.x;

    double s0 = 0, s1 = 0, s2 = 0, s3 = 0;
    #pragma unroll 4
    for (int tok = 0; tok < 16; ++tok) {
        const float4 v = *(const float4*)(xc + tok * DD + t * 4);
        bf16_4 o;
        o[0] = (__bf16)v.x; o[1] = (__bf16)v.y; o[2] = (__bf16)v.z; o[3] = (__bf16)v.w;
        *(bf16_4*)(ac + tok * DD + t * 4) = o;
        s0 += (double)v.x; s1 += (double)v.y; s2 += (double)v.z; s3 += (double)v.w;
    }
    double* c = csum_p + ((size_t)(chunk * 8 + tg)) * DD + t * 4;
    c[0] = s0; c[1] = s1; c[2] = s2; c[3] = s3;
}

// ---------------- router stage 2: reduce partials, proj + expert pick --------
__global__ __launch_bounds__(256) void router2_kernel(
    const double* __restrict__ csum_p, const float* __restrict__ hyp,
    int* __restrict__ eidx)
{
    const int chunk = blockIdx.x;
    const int t = threadIdx.x;
    double pj[NBITS];
    #pragma unroll
    for (int j = 0; j < NBITS; ++j) pj[j] = 0.0;
    #pragma unroll
    for (int i = 0; i < 4; ++i) {
        const int d = t + i * 256;
        double cs = 0.0;
        #pragma unroll
        for (int tg = 0; tg < 8; ++tg)
            cs += csum_p[((size_t)(chunk * 8 + tg)) * DD + d];
        const double emb = cs * (1.0 / 128.0);
        #pragma unroll
        for (int j = 0; j < NBITS; ++j)
            pj[j] += emb * (double)hyp[d * NBITS + j];
    }
    #pragma unroll
    for (int off = 32; off > 0; off >>= 1) {
        #pragma unroll
        for (int j = 0; j < NBITS; ++j)
            pj[j] += __shfl_down(pj[j], off, 64);
    }
    __shared__ double red[4][NBITS];
    const int wave = t >> 6, lane = t & 63;
    if (lane == 0) {
        #pragma unroll
        for (int j = 0; j < NBITS; ++j) red[wave][j] = pj[j];
    }
    __syncthreads();
    if (t == 0) {
        int e1 = 0, weakest = 0;
        double best = 1e300;
        #pragma unroll
        for (int j = 0; j < NBITS; ++j) {
            double p = red[0][j] + red[1][j] + red[2][j] + red[3][j];
            if (p > 0.0) e1 |= (1 << j);
            double aa = fabs(p);
            if (aa < best) { best = aa; weakest = j; }  // first-min, like argmin
        }
        eidx[chunk * 2 + 0] = e1;
        eidx[chunk * 2 + 1] = e1 ^ (1 << weakest);
    }
}

// ---------------- W fp32 [e][k][n] -> bf16 Wt in GEMM-tile order ------------
__global__ __launch_bounds__(256) void wcvt_kernel(
    const float* __restrict__ W, __bf16* __restrict__ WtSw,
    const int* __restrict__ eidx)
{
    __shared__ float tile[32 * 129];
    __shared__ int s_used;

    const int bx = blockIdx.x;
    const int kh = bx & 1;
    const int nt = (bx >> 1) & 7;
    const int e  = bx >> 4;
    const int t = threadIdx.x;

    if (t == 0) s_used = 0;
    __syncthreads();
    if (eidx[t] == e) s_used = 1;
    __syncthreads();
    if (!s_used) return;

    const float* We = W + (size_t)e * DD * DD + nt * 128;
    __bf16* base_ent = WtSw + (size_t)(e * 8 + nt) * WT_PER_ENT;

    for (int it = 0; it < 16; ++it) {
        const int k0 = kh * 512 + it * 32;
        const int s  = kh * 16 + it;
        #pragma unroll
        for (int p = 0; p < 4; ++p) {
            const int idx = p * 256 + t;
            const int kr  = idx >> 5;
            const int nc4 = idx & 31;
            const float4 v = *(const float4*)(We + (size_t)(k0 + kr) * DD + nc4 * 4);
            float* dst = &tile[kr * 129 + nc4 * 4];
            dst[0] = v.x; dst[1] = v.y; dst[2] = v.z; dst[3] = v.w;
        }
        __syncthreads();
        #pragma unroll
        for (int c = 0; c < 2; ++c) {
            const int cell = c * 256 + t;
            const int l  = cell & 63;
            const int rb = cell >> 6;
            const int q  = l >> 4;
            const int lr = l & 15;
            bf16_8 o;
            #pragma unroll
            for (int j = 0; j < 8; ++j)
                o[j] = (__bf16)tile[(q * 8 + j) * 129 + rb * 16 + lr];
            *(bf16_8*)(base_ent + ((size_t)s * 8 + rb) * 512 + l * 8) = o;
        }
        __syncthreads();
    }
}

// ---------------- GEMM dual-expert, 8-phase deep pipeline -------------------
// Block: 512 thr (8 waves, 2M x 4N), tile 128x256, virtual K=2048
// (kt 0..15 -> e0, 16..31 -> e1). BK=64. LDS 96KB dynamic:
//   A[c][h][rb][512]  c=dbuf, h=k-half(32), rb=row-block(16r)   -> 32KB
//   B[c][s][ntl][cb][512] s=k-half, ntl=128-col grp, cb=col-blk -> 64KB
// Per K-tile 4 phases; per-wave stage issues age-aligned with consumption:
//   #1 A-h0 | #2 B-s0-early | #3 B-s0-late | #4 A-h1 | #5 B-s1-early | #6 B-s1-late
// Phase bodies issue (2,2,2,0) for tile t+1; waits vmcnt(5,5,6,4), tail peeled.
__global__ __launch_bounds__(512) void ffn_gemm_bf16(
    const __bf16* __restrict__ Abf,      // [NCHUNK*128, 1024] row-major
    const __bf16* __restrict__ WtSw,     // tile-order (see above)
    const int* __restrict__ eidx,
    float* __restrict__ out)
{
    extern __shared__ char smem[];
    __bf16* Ab = (__bf16*)smem;                    // [2][2][8][512]
    __bf16* Bb = (__bf16*)(smem + 32768);          // [2][2][2][8][512]
#define A_OFF(c, h, rb)      ((((c) * 2 + (h)) * 8 + (rb)) * 512)
#define B_OFF(c, s, ntl, cb) (((((c) * 2 + (s)) * 2 + (ntl)) * 8 + (cb)) * 512)

    const int bx0 = blockIdx.x;
    const int xcd = bx0 & 7;
    const int j = bx0 >> 3;                 // 0..63
    const int chunk = xcd * 16 + (j >> 2);  // 16 chunks per XCD -> A L2 reuse
    const int nb = j & 3;                   // 256-col group

    const int t = threadIdx.x;
    const int lane = t & 63;
    const int wave = t >> 6;     // 0..7
    const int wm = wave >> 2;    // 0..1
    const int wn = wave & 3;     // 0..3
    const int lr = lane & 15;
    const int q  = lane >> 4;
    const int ntl_r = wn >> 1;          // B col-half this wave reads
    const int cbb   = (wn & 1) * 4;     // col-block base within the half

    const int e0 = eidx[chunk * 2 + 0];
    const int e1 = eidx[chunk * 2 + 1];

    const __bf16* Ag  = Abf + (size_t)chunk * CHUNKD * DD;
    const __bf16* AgS = Ag + (size_t)(wave * 16 + lr) * DD + q * 8;  // stage src (rb=wave)

    const int ntl_s = wave >> 2;            // B col-half this wave stages
    const int ib    = wave & 3;
    const int cbE   = ib + ((ib >> 1) << 1);   // {0,1,4,5}
    const int cbL   = cbE + 2;                 // {2,3,6,7}
    const __bf16* BgE0 = WtSw + (size_t)(e0 * 8 + nb * 2 + ntl_s) * WT_PER_ENT + lane * 8;
    const __bf16* BgE1 = WtSw + (size_t)(e1 * 8 + nb * 2 + ntl_s) * WT_PER_ENT + lane * 8;

    floatx4 acc[4][4] = {};
    bf16_8 af[4], bbv[2];

#define ISSUE_A(c, tt, h)                                                      \
    __builtin_amdgcn_global_load_lds(                                          \
        (const __attribute__((address_space(1))) void*)(AgS + ((tt) & 15) * 64 + (h) * 32), \
        (__attribute__((address_space(3))) void*)(&Ab[A_OFF(c, h, wave)]), 16, 0, 0)

#define ISSUE_B(c, tt, s, cb) do {                                             \
    const __bf16* bsrc_ = ((tt) < 16 ? BgE0 : BgE1)                            \
        + ((size_t)((((tt) & 15) * 2 + (s)) * 8 + (cb))) * 512;                \
    __builtin_amdgcn_global_load_lds(                                          \
        (const __attribute__((address_space(1))) void*)bsrc_,                  \
        (__attribute__((address_space(3))) void*)(&Bb[B_OFF(c, s, ntl_s, cb)]), 16, 0, 0); \
} while (0)

#define DS_AF(c, h) do {                                                       \
    _Pragma("unroll")                                                          \
    for (int mt = 0; mt < 4; ++mt)                                             \
        af[mt] = *(const bf16_8*)(&Ab[A_OFF(c, h, wm * 4 + mt) + lane * 8]);   \
} while (0)

#define DS_BB(c, s, ntA, ntB) do {                                             \
    bbv[0] = *(const bf16_8*)(&Bb[B_OFF(c, s, ntl_r, cbb + (ntA)) + lane * 8]); \
    bbv[1] = *(const bf16_8*)(&Bb[B_OFF(c, s, ntl_r, cbb + (ntB)) + lane * 8]); \
} while (0)

#define MFMA8(ntA, ntB) do {                                                   \
    __builtin_amdgcn_s_setprio(1);                                             \
    _Pragma("unroll")                                                          \
    for (int mt = 0; mt < 4; ++mt) {                                           \
        acc[mt][ntA] = __builtin_amdgcn_mfma_f32_16x16x32_bf16(                \
            af[mt], bbv[0], acc[mt][ntA], 0, 0, 0);                            \
        acc[mt][ntB] = __builtin_amdgcn_mfma_f32_16x16x32_bf16(                \
            af[mt], bbv[1], acc[mt][ntB], 0, 0, 0);                            \
    }                                                                          \
    __builtin_amdgcn_s_setprio(0);                                             \
} while (0)

#define VBAR(N) do {                                                           \
    asm volatile("s_waitcnt vmcnt(" #N ")" ::: "memory");                      \
    __builtin_amdgcn_s_barrier();                                              \
} while (0)

    // prologue: tile 0, issues in age order #1..#6
    ISSUE_A(0, 0, 0);
    ISSUE_B(0, 0, 0, cbE);
    ISSUE_B(0, 0, 0, cbL);
    ISSUE_A(0, 0, 1);
    ISSUE_B(0, 0, 1, cbE);
    ISSUE_B(0, 0, 1, cbL);
    VBAR(4);   // guards tile0-P0 reads (#1,#2)

    #pragma unroll 1
    for (int tt = 0; tt < 31; ++tt) {
        const int c  = tt & 1;
        const int nx = c ^ 1;
        // P0: compute (h0, nt{0,1}); issue t+1 #1,#2
        DS_AF(c, 0); DS_BB(c, 0, 0, 1);
        ISSUE_A(nx, tt + 1, 0); ISSUE_B(nx, tt + 1, 0, cbE);
        VBAR(5);                 // guards P1 read (#3)
        MFMA8(0, 1);
        // P1: compute (h0, nt{2,3}); issue #3,#4
        DS_BB(c, 0, 2, 3);
        ISSUE_B(nx, tt + 1, 0, cbL); ISSUE_A(nx, tt + 1, 1);
        VBAR(5);                 // guards P2 reads (#4,#5)
        MFMA8(2, 3);
        // P2: compute (h1, nt{0,1}); issue #5,#6
        DS_AF(c, 1); DS_BB(c, 1, 0, 1);
        ISSUE_B(nx, tt + 1, 1, cbE); ISSUE_B(nx, tt + 1, 1, cbL);
        VBAR(6);                 // guards P3 read (#6)
        MFMA8(0, 1);
        // P3: compute (h1, nt{2,3}); no issues
        DS_BB(c, 1, 2, 3);
        VBAR(4);                 // guards next tile P0 reads (#1,#2)
        MFMA8(2, 3);
    }
    // peeled tile 31 (c=1): no issues, exact drain counts
    {
        DS_AF(1, 0); DS_BB(1, 0, 0, 1);
        VBAR(3);
        MFMA8(0, 1);
        DS_BB(1, 0, 2, 3);
        VBAR(1);
        MFMA8(2, 3);
        DS_AF(1, 1); DS_BB(1, 1, 0, 1);
        VBAR(0);
        MFMA8(0, 1);
        DS_BB(1, 1, 2, 3);
        MFMA8(2, 3);
    }

#undef ISSUE_A
#undef ISSUE_B
#undef DS_AF
#undef DS_BB
#undef MFMA8
#undef VBAR
#undef A_OFF
#undef B_OFF

    const size_t orow0 = (size_t)chunk * CHUNKD;
    const int n0 = nb * 256;
    #pragma unroll
    for (int mt = 0; mt < 4; ++mt) {
        #pragma unroll
        for (int nt = 0; nt < 4; ++nt) {
            const int col = n0 + wn * 64 + nt * 16 + lr;
            #pragma unroll
            for (int r = 0; r < 4; ++r) {
                const int row = wm * 64 + mt * 16 + q * 4 + r;
                out[(orow0 + row) * DD + col] = acc[mt][nt][r] * 0.5f;
            }
        }
    }
}

// ======================= fallback path (R1-style, ~34 MB ws) ================
__global__ __launch_bounds__(256) void router_kernel(
    const float* __restrict__ x, const float* __restrict__ hyp,
    int* __restrict__ eidx)
{
    const int chunk = blockIdx.x;
    const int t = threadIdx.x;
    const float* xc = x + (size_t)chunk * CHUNKD * DD;
    double cs[4] = {0.0, 0.0, 0.0, 0.0};
    for (int tok = 0; tok < CHUNKD; ++tok) {
        const float* row = xc + tok * DD;
        #pragma unroll
        for (int i = 0; i < 4; ++i) cs[i] += (double)row[t + i * 256];
    }
    double pj[NBITS];
    #pragma unroll
    for (int j = 0; j < NBITS; ++j) pj[j] = 0.0;
    #pragma unroll
    for (int i = 0; i < 4; ++i) {
        const int d = t + i * 256;
        const double emb = cs[i] * (1.0 / 128.0);
        #pragma unroll
        for (int j = 0; j < NBITS; ++j) pj[j] += emb * (double)hyp[d * NBITS + j];
    }
    #pragma unroll
    for (int off = 32; off > 0; off >>= 1) {
        #pragma unroll
        for (int j = 0; j < NBITS; ++j) pj[j] += __shfl_down(pj[j], off, 64);
    }
    __shared__ double red[4][NBITS];
    const int wave = t >> 6, lane = t & 63;
    if (lane == 0) {
        #pragma unroll
        for (int j = 0; j < NBITS; ++j) red[wave][j] = pj[j];
    }
    __syncthreads();
    if (t == 0) {
        int e1 = 0, weakest = 0;
        double best = 1e300;
        #pragma unroll
        for (int j = 0; j < NBITS; ++j) {
            double p = red[0][j] + red[1][j] + red[2][j] + red[3][j];
            if (p > 0.0) e1 |= (1 << j);
            double a = fabs(p);
            if (a < best) { best = a; weakest = j; }
        }
        eidx[chunk * 2 + 0] = e1;
        eidx[chunk * 2 + 1] = e1 ^ (1 << weakest);
    }
}

__global__ __launch_bounds__(256) void cvt_x_kernel(
    const float* __restrict__ x, __bf16* __restrict__ a)
{
    const size_t i = ((size_t)blockIdx.x * 256 + threadIdx.x) * 4;
    const float4 v = *(const float4*)(x + i);
    bf16_4 o;
    o[0] = (__bf16)v.x; o[1] = (__bf16)v.y; o[2] = (__bf16)v.z; o[3] = (__bf16)v.w;
    *(bf16_4*)(a + i) = o;
}

__global__ __launch_bounds__(256) void ffn_gemm_fp32w(
    const __bf16* __restrict__ Abf, const float* __restrict__ W,
    const int* __restrict__ eidx, float* __restrict__ out)
{
    __shared__ __bf16 Als[128 * 32];
    __shared__ __bf16 Bls[128 * 32];
    const int bx = blockIdx.x;
    const int chunk = bx >> 3;
    const int n0 = (bx & 7) * 128;
    const int t = threadIdx.x;
    const int lane = t & 63;
    const int wave = t >> 6;
    const int wm = wave >> 1;
    const int wn = wave & 1;
    const int lr = lane & 15;
    const int q  = lane >> 4;
    const int ee[2] = {eidx[chunk * 2 + 0], eidx[chunk * 2 + 1]};
    const __bf16* Ag = Abf + (size_t)chunk * CHUNKD * DD;
    const int a_col = (lane & 3) * 8;
    const int a_rsub = lane >> 2;
    floatx4 acc[4][4] = {};
    for (int xp = 0; xp < 2; ++xp) {
        const float* We = W + (size_t)ee[xp] * (DD * DD) + n0;
        for (int k0 = 0; k0 < DD; k0 += 32) {
            float bv[2][8];
            #pragma unroll
            for (int rep = 0; rep < 2; ++rep) {
                const int nb = wave * 16 + lr + rep * 64;
                const float* src = We + (size_t)(k0 + q * 8) * DD + nb;
                #pragma unroll
                for (int j = 0; j < 8; ++j) bv[rep][j] = src[(size_t)j * DD];
            }
            #pragma unroll
            for (int i = 0; i < 2; ++i) {
                const __bf16* ga = Ag + (size_t)((wave * 2 + i) * 16 + a_rsub) * DD + k0 + a_col;
                __builtin_amdgcn_global_load_lds(
                    (const __attribute__((address_space(1))) void*)ga,
                    (__attribute__((address_space(3))) void*)(&Als[(wave * 2 + i) * 512]),
                    16, 0, 0);
            }
            #pragma unroll
            for (int rep = 0; rep < 2; ++rep) {
                const int nb = wave * 16 + lr + rep * 64;
                bf16_8 bw;
                #pragma unroll
                for (int j = 0; j < 8; ++j) bw[j] = (__bf16)bv[rep][j];
                *(bf16_8*)(&Bls[nb * 32 + q * 8]) = bw;
            }
            __syncthreads();
            bf16_8 af2[4], bfr[4];
            #pragma unroll
            for (int mt = 0; mt < 4; ++mt)
                af2[mt] = *(const bf16_8*)(&Als[(wm * 64 + mt * 16 + lr) * 32 + q * 8]);
            #pragma unroll
            for (int nt = 0; nt < 4; ++nt)
                bfr[nt] = *(const bf16_8*)(&Bls[(wn * 64 + nt * 16 + lr) * 32 + q * 8]);
            #pragma unroll
            for (int mt = 0; mt < 4; ++mt) {
                #pragma unroll
                for (int nt = 0; nt < 4; ++nt)
                    acc[mt][nt] = __builtin_amdgcn_mfma_f32_16x16x32_bf16(
                        af2[mt], bfr[nt], acc[mt][nt], 0, 0, 0);
            }
            __syncthreads();
        }
    }
    const size_t orow0 = (size_t)chunk * CHUNKD;
    #pragma unroll
    for (int mt = 0; mt < 4; ++mt) {
        #pragma unroll
        for (int nt = 0; nt < 4; ++nt) {
            const int col = n0 + wn * 64 + nt * 16 + lr;
            #pragma unroll
            for (int r = 0; r < 4; ++r) {
                const int row = wm * 64 + mt * 16 + q * 4 + r;
                out[(orow0 + row) * DD + col] = acc[mt][nt][r] * 0.5f;
            }
        }
    }
}

extern "C" void kernel_launch(void* const* d_in, const int* in_sizes, int n_in,
                              void* d_out, int out_size, void* d_ws, size_t ws_size,
                              hipStream_t stream) {
    const float* x   = (const float*)d_in[0];   // [4,4096,1024]
    const float* W   = (const float*)d_in[1];   // [64,1024,1024]
    const float* hyp = (const float*)d_in[2];   // [1024,6]
    float* out = (float*)d_out;

    // ws layout: eidx 4KB | csum_p 8MB | A bf16 33.5MB | WtSw bf16 128MB
    const size_t off_eidx = 0;
    const size_t off_csum = 4096;
    const size_t off_a    = off_csum + (size_t)NCHUNK * 8 * DD * 8;
    const size_t off_wt   = off_a + (size_t)NCHUNK * CHUNKD * DD * 2;
    const size_t need     = off_wt + (size_t)ED * DD * DD * 2;

    int* eidx = (int*)((char*)d_ws + off_eidx);
    __bf16* Abf = (__bf16*)((char*)d_ws + off_a);

    if (ws_size >= need) {
        double* csum_p = (double*)((char*)d_ws + off_csum);
        __bf16* WtSw = (__bf16*)((char*)d_ws + off_wt);
        sum_cvt_kernel<<<NCHUNK * 8, 256, 0, stream>>>(x, Abf, csum_p);
        router2_kernel<<<NCHUNK, 256, 0, stream>>>(csum_p, hyp, eidx);
        wcvt_kernel<<<ED * 16, 256, 0, stream>>>(W, WtSw, eidx);
        ffn_gemm_bf16<<<512, 512, 98304, stream>>>(Abf, WtSw, eidx, out);
    } else {
        __bf16* Abf2 = (__bf16*)((char*)d_ws + 1024);
        router_kernel<<<NCHUNK, 256, 0, stream>>>(x, hyp, eidx);
        cvt_x_kernel<<<(BD * LD * DD) / (256 * 4), 256, 0, stream>>>(x, Abf2);
        ffn_gemm_fp32w<<<NCHUNK * 8, 256, 0, stream>>>(Abf2, W, eidx, out);
    }
}

// Round 4
// 527.577 us; speedup vs baseline: 1.0041x; 1.0041x over previous
//
#include <hip/hip_runtime.h>
#include <hip/hip_bf16.h>

// SparseFFN R7: revert gemm body to R4's proven 2-barrier structure (best
// occupancy, R5/R6 pipelines were null); add expert-locality scheduling:
// chunks counting-sorted by e0 (stable, done serially by wcvt block 0,
// zero extra dispatches), gemm blocks mapped so each XCD owns a contiguous
// run of sorted chunks with all 8 ntb-blocks of a chunk dispatch-adjacent
// on the same XCD -> same-expert B-panels become L2-hits instead of L3.

#define BD 4
#define LD 4096
#define DD 1024
#define ED 64
#define CHUNKD 128
#define NBITS 6
#define NCHUNK 128   // B * L/CHUNK

typedef __bf16 bf16_8 __attribute__((ext_vector_type(8)));
typedef __bf16 bf16_4 __attribute__((ext_vector_type(4)));
typedef float floatx4 __attribute__((ext_vector_type(4)));

// Wt tile-order cell: [e][nt(8)][s(32)][rb(8)][lane(64)] x 8 bf16 (16B).
// cell(e,nt,s,rb,l) holds W[e][k = s*32 + (l>>4)*8 + j][n = nt*128 + rb*16 + (l&15)], j=0..7
#define WT_PER_ENT  131072          // 32*8*64*8 elems = 256 KB per (e,nt)

// ---------------- fused: x -> bf16 A (row-major), per-(chunk,tg) fp64 col sums
__global__ __launch_bounds__(256) void sum_cvt_kernel(
    const float* __restrict__ x, __bf16* __restrict__ a, double* __restrict__ csum_p)
{
    const int chunk = blockIdx.x >> 3;
    const int tg = blockIdx.x & 7;
    const size_t base = (size_t)chunk * CHUNKD * DD + (size_t)tg * 16 * DD;
    const float* xc = x + base;
    __bf16* ac = a + base;
    const int t = threadIdx.x;

    double s0 = 0, s1 = 0, s2 = 0, s3 = 0;
    #pragma unroll 4
    for (int tok = 0; tok < 16; ++tok) {
        const float4 v = *(const float4*)(xc + tok * DD + t * 4);
        bf16_4 o;
        o[0] = (__bf16)v.x; o[1] = (__bf16)v.y; o[2] = (__bf16)v.z; o[3] = (__bf16)v.w;
        *(bf16_4*)(ac + tok * DD + t * 4) = o;
        s0 += (double)v.x; s1 += (double)v.y; s2 += (double)v.z; s3 += (double)v.w;
    }
    double* c = csum_p + ((size_t)(chunk * 8 + tg)) * DD + t * 4;
    c[0] = s0; c[1] = s1; c[2] = s2; c[3] = s3;
}

// ---------------- router stage 2: reduce partials, proj + expert pick --------
__global__ __launch_bounds__(256) void router2_kernel(
    const double* __restrict__ csum_p, const float* __restrict__ hyp,
    int* __restrict__ eidx)
{
    const int chunk = blockIdx.x;
    const int t = threadIdx.x;
    double pj[NBITS];
    #pragma unroll
    for (int j = 0; j < NBITS; ++j) pj[j] = 0.0;
    #pragma unroll
    for (int i = 0; i < 4; ++i) {
        const int d = t + i * 256;
        double cs = 0.0;
        #pragma unroll
        for (int tg = 0; tg < 8; ++tg)
            cs += csum_p[((size_t)(chunk * 8 + tg)) * DD + d];
        const double emb = cs * (1.0 / 128.0);
        #pragma unroll
        for (int j = 0; j < NBITS; ++j)
            pj[j] += emb * (double)hyp[d * NBITS + j];
    }
    #pragma unroll
    for (int off = 32; off > 0; off >>= 1) {
        #pragma unroll
        for (int j = 0; j < NBITS; ++j)
            pj[j] += __shfl_down(pj[j], off, 64);
    }
    __shared__ double red[4][NBITS];
    const int wave = t >> 6, lane = t & 63;
    if (lane == 0) {
        #pragma unroll
        for (int j = 0; j < NBITS; ++j) red[wave][j] = pj[j];
    }
    __syncthreads();
    if (t == 0) {
        int e1 = 0, weakest = 0;
        double best = 1e300;
        #pragma unroll
        for (int j = 0; j < NBITS; ++j) {
            double p = red[0][j] + red[1][j] + red[2][j] + red[3][j];
            if (p > 0.0) e1 |= (1 << j);
            double aa = fabs(p);
            if (aa < best) { best = aa; weakest = j; }  // first-min, like argmin
        }
        eidx[chunk * 2 + 0] = e1;
        eidx[chunk * 2 + 1] = e1 ^ (1 << weakest);
    }
}

// ---------------- W fp32 [e][k][n] -> bf16 Wt in GEMM-tile order ------------
// Block 0 thread 0 additionally counting-sorts chunks by e0 into perm
// (stable; pure perf hint for the gemm's dispatch->expert locality).
__global__ __launch_bounds__(256) void wcvt_kernel(
    const float* __restrict__ W, __bf16* __restrict__ WtSw,
    const int* __restrict__ eidx, int* __restrict__ perm)
{
    __shared__ float tile[32 * 129];
    __shared__ int s_used;
    __shared__ int sortbuf[128];   // cnt[64] + pos[64], used by block 0 t0 only

    const int bx = blockIdx.x;
    const int kh = bx & 1;
    const int nt = (bx >> 1) & 7;
    const int e  = bx >> 4;
    const int t = threadIdx.x;

    if (bx == 0 && t == 0) {
        int* cnt = sortbuf;
        int* pos = sortbuf + 64;
        for (int i = 0; i < 64; ++i) cnt[i] = 0;
        for (int c = 0; c < NCHUNK; ++c) cnt[eidx[c * 2]]++;
        int s = 0;
        for (int i = 0; i < 64; ++i) { pos[i] = s; s += cnt[i]; }
        for (int c = 0; c < NCHUNK; ++c) perm[pos[eidx[c * 2]]++] = c;
    }

    if (t == 0) s_used = 0;
    __syncthreads();
    if (eidx[t] == e) s_used = 1;
    __syncthreads();
    if (!s_used) return;

    const float* We = W + (size_t)e * DD * DD + nt * 128;
    __bf16* base_ent = WtSw + (size_t)(e * 8 + nt) * WT_PER_ENT;

    for (int it = 0; it < 16; ++it) {
        const int k0 = kh * 512 + it * 32;
        const int s  = kh * 16 + it;
        #pragma unroll
        for (int p = 0; p < 4; ++p) {
            const int idx = p * 256 + t;
            const int kr  = idx >> 5;
            const int nc4 = idx & 31;
            const float4 v = *(const float4*)(We + (size_t)(k0 + kr) * DD + nc4 * 4);
            float* dst = &tile[kr * 129 + nc4 * 4];
            dst[0] = v.x; dst[1] = v.y; dst[2] = v.z; dst[3] = v.w;
        }
        __syncthreads();
        #pragma unroll
        for (int c = 0; c < 2; ++c) {
            const int cell = c * 256 + t;
            const int l  = cell & 63;
            const int rb = cell >> 6;
            const int q  = l >> 4;
            const int lr = l & 15;
            bf16_8 o;
            #pragma unroll
            for (int j = 0; j < 8; ++j)
                o[j] = (__bf16)tile[(q * 8 + j) * 129 + rb * 16 + lr];
            *(bf16_8*)(base_ent + ((size_t)s * 8 + rb) * 512 + l * 8) = o;
        }
        __syncthreads();
    }
}

// ---------------- GEMM dual-expert: out = 0.5*(A@W[e0] + A@W[e1]) -----------
// R4 body (2-barrier, 24KB LDS, 4 waves). Mapping: xcd = bx&7 gets 16
// consecutive e0-sorted chunks; a chunk's 8 ntb-blocks are dispatch-adjacent
// (stride-8 indices -> same XCD under round-robin) for A + B L2 reuse.
__global__ __launch_bounds__(256) void ffn_gemm_bf16(
    const __bf16* __restrict__ Abf,      // [NCHUNK*128, 1024] row-major
    const __bf16* __restrict__ WtSw,     // tile-order (see above)
    const int* __restrict__ eidx,
    const int* __restrict__ perm,
    float* __restrict__ out)
{
    __shared__ __bf16 Als[8 * 512];      // 8 KB
    __shared__ __bf16 B0ls[8 * 512];     // 8 KB
    __shared__ __bf16 B1ls[8 * 512];     // 8 KB

    const int bx = blockIdx.x;
    const int xcd = bx & 7;
    const int g = bx >> 3;               // 0..127
    const int chunk = perm[xcd * 16 + (g >> 3)];
    const int ntb = g & 7;

    const int t = threadIdx.x;
    const int lane = t & 63;
    const int wave = t >> 6;
    const int wm = wave >> 1;
    const int wn = wave & 1;
    const int lr = lane & 15;
    const int q  = lane >> 4;

    const int e0 = eidx[chunk * 2 + 0];
    const int e1 = eidx[chunk * 2 + 1];

    const __bf16* Ag = Abf + (size_t)chunk * CHUNKD * DD;
    const __bf16* Bg0 = WtSw + (size_t)(e0 * 8 + ntb) * WT_PER_ENT + lane * 8;
    const __bf16* Bg1 = WtSw + (size_t)(e1 * 8 + ntb) * WT_PER_ENT + lane * 8;

    // A issue source for this wave's two row-blocks
    const int rb0 = wave * 2;
    const __bf16* AgW0 = Ag + (size_t)(rb0 * 16 + lr) * DD + q * 8;
    const __bf16* AgW1 = Ag + (size_t)((rb0 + 1) * 16 + lr) * DD + q * 8;

    floatx4 acc[4][4] = {};

    for (int ks = 0; ks < 32; ++ks) {
        const int k0 = ks * 32;
        __builtin_amdgcn_global_load_lds(
            (const __attribute__((address_space(1))) void*)(AgW0 + k0),
            (__attribute__((address_space(3))) void*)(&Als[rb0 * 512]), 16, 0, 0);
        __builtin_amdgcn_global_load_lds(
            (const __attribute__((address_space(1))) void*)(AgW1 + k0),
            (__attribute__((address_space(3))) void*)(&Als[(rb0 + 1) * 512]), 16, 0, 0);
        #pragma unroll
        for (int i = 0; i < 2; ++i) {
            const int rb = rb0 + i;
            __builtin_amdgcn_global_load_lds(
                (const __attribute__((address_space(1))) void*)(Bg0 + ((size_t)ks * 8 + rb) * 512),
                (__attribute__((address_space(3))) void*)(&B0ls[rb * 512]), 16, 0, 0);
            __builtin_amdgcn_global_load_lds(
                (const __attribute__((address_space(1))) void*)(Bg1 + ((size_t)ks * 8 + rb) * 512),
                (__attribute__((address_space(3))) void*)(&B1ls[rb * 512]), 16, 0, 0);
        }
        __syncthreads();

        bf16_8 af[4], bb[4];
        #pragma unroll
        for (int mt = 0; mt < 4; ++mt)
            af[mt] = *(const bf16_8*)(&Als[(wm * 4 + mt) * 512 + lane * 8]);
        #pragma unroll
        for (int nt = 0; nt < 4; ++nt)
            bb[nt] = *(const bf16_8*)(&B0ls[(wn * 4 + nt) * 512 + lane * 8]);
        #pragma unroll
        for (int mt = 0; mt < 4; ++mt) {
            #pragma unroll
            for (int nt = 0; nt < 4; ++nt)
                acc[mt][nt] = __builtin_amdgcn_mfma_f32_16x16x32_bf16(
                    af[mt], bb[nt], acc[mt][nt], 0, 0, 0);
        }
        #pragma unroll
        for (int nt = 0; nt < 4; ++nt)
            bb[nt] = *(const bf16_8*)(&B1ls[(wn * 4 + nt) * 512 + lane * 8]);
        #pragma unroll
        for (int mt = 0; mt < 4; ++mt) {
            #pragma unroll
            for (int nt = 0; nt < 4; ++nt)
                acc[mt][nt] = __builtin_amdgcn_mfma_f32_16x16x32_bf16(
                    af[mt], bb[nt], acc[mt][nt], 0, 0, 0);
        }
        __syncthreads();
    }

    const size_t orow0 = (size_t)chunk * CHUNKD;
    const int n0 = ntb * 128;
    #pragma unroll
    for (int mt = 0; mt < 4; ++mt) {
        #pragma unroll
        for (int nt = 0; nt < 4; ++nt) {
            const int col = n0 + wn * 64 + nt * 16 + lr;
            #pragma unroll
            for (int r = 0; r < 4; ++r) {
                const int row = wm * 64 + mt * 16 + q * 4 + r;
                out[(orow0 + row) * DD + col] = acc[mt][nt][r] * 0.5f;
            }
        }
    }
}

// ======================= fallback path (R1-style, ~34 MB ws) ================
__global__ __launch_bounds__(256) void router_kernel(
    const float* __restrict__ x, const float* __restrict__ hyp,
    int* __restrict__ eidx)
{
    const int chunk = blockIdx.x;
    const int t = threadIdx.x;
    const float* xc = x + (size_t)chunk * CHUNKD * DD;
    double cs[4] = {0.0, 0.0, 0.0, 0.0};
    for (int tok = 0; tok < CHUNKD; ++tok) {
        const float* row = xc + tok * DD;
        #pragma unroll
        for (int i = 0; i < 4; ++i) cs[i] += (double)row[t + i * 256];
    }
    double pj[NBITS];
    #pragma unroll
    for (int j = 0; j < NBITS; ++j) pj[j] = 0.0;
    #pragma unroll
    for (int i = 0; i < 4; ++i) {
        const int d = t + i * 256;
        const double emb = cs[i] * (1.0 / 128.0);
        #pragma unroll
        for (int j = 0; j < NBITS; ++j) pj[j] += emb * (double)hyp[d * NBITS + j];
    }
    #pragma unroll
    for (int off = 32; off > 0; off >>= 1) {
        #pragma unroll
        for (int j = 0; j < NBITS; ++j) pj[j] += __shfl_down(pj[j], off, 64);
    }
    __shared__ double red[4][NBITS];
    const int wave = t >> 6, lane = t & 63;
    if (lane == 0) {
        #pragma unroll
        for (int j = 0; j < NBITS; ++j) red[wave][j] = pj[j];
    }
    __syncthreads();
    if (t == 0) {
        int e1 = 0, weakest = 0;
        double best = 1e300;
        #pragma unroll
        for (int j = 0; j < NBITS; ++j) {
            double p = red[0][j] + red[1][j] + red[2][j] + red[3][j];
            if (p > 0.0) e1 |= (1 << j);
            double a = fabs(p);
            if (a < best) { best = a; weakest = j; }
        }
        eidx[chunk * 2 + 0] = e1;
        eidx[chunk * 2 + 1] = e1 ^ (1 << weakest);
    }
}

__global__ __launch_bounds__(256) void cvt_x_kernel(
    const float* __restrict__ x, __bf16* __restrict__ a)
{
    const size_t i = ((size_t)blockIdx.x * 256 + threadIdx.x) * 4;
    const float4 v = *(const float4*)(x + i);
    bf16_4 o;
    o[0] = (__bf16)v.x; o[1] = (__bf16)v.y; o[2] = (__bf16)v.z; o[3] = (__bf16)v.w;
    *(bf16_4*)(a + i) = o;
}

__global__ __launch_bounds__(256) void ffn_gemm_fp32w(
    const __bf16* __restrict__ Abf, const float* __restrict__ W,
    const int* __restrict__ eidx, float* __restrict__ out)
{
    __shared__ __bf16 Als[128 * 32];
    __shared__ __bf16 Bls[128 * 32];
    const int bx = blockIdx.x;
    const int chunk = bx >> 3;
    const int n0 = (bx & 7) * 128;
    const int t = threadIdx.x;
    const int lane = t & 63;
    const int wave = t >> 6;
    const int wm = wave >> 1;
    const int wn = wave & 1;
    const int lr = lane & 15;
    const int q  = lane >> 4;
    const int ee[2] = {eidx[chunk * 2 + 0], eidx[chunk * 2 + 1]};
    const __bf16* Ag = Abf + (size_t)chunk * CHUNKD * DD;
    const int a_col = (lane & 3) * 8;
    const int a_rsub = lane >> 2;
    floatx4 acc[4][4] = {};
    for (int xp = 0; xp < 2; ++xp) {
        const float* We = W + (size_t)ee[xp] * (DD * DD) + n0;
        for (int k0 = 0; k0 < DD; k0 += 32) {
            float bv[2][8];
            #pragma unroll
            for (int rep = 0; rep < 2; ++rep) {
                const int nb = wave * 16 + lr + rep * 64;
                const float* src = We + (size_t)(k0 + q * 8) * DD + nb;
                #pragma unroll
                for (int j = 0; j < 8; ++j) bv[rep][j] = src[(size_t)j * DD];
            }
            #pragma unroll
            for (int i = 0; i < 2; ++i) {
                const __bf16* ga = Ag + (size_t)((wave * 2 + i) * 16 + a_rsub) * DD + k0 + a_col;
                __builtin_amdgcn_global_load_lds(
                    (const __attribute__((address_space(1))) void*)ga,
                    (__attribute__((address_space(3))) void*)(&Als[(wave * 2 + i) * 512]),
                    16, 0, 0);
            }
            #pragma unroll
            for (int rep = 0; rep < 2; ++rep) {
                const int nb = wave * 16 + lr + rep * 64;
                bf16_8 bw;
                #pragma unroll
                for (int j = 0; j < 8; ++j) bw[j] = (__bf16)bv[rep][j];
                *(bf16_8*)(&Bls[nb * 32 + q * 8]) = bw;
            }
            __syncthreads();
            bf16_8 af2[4], bfr[4];
            #pragma unroll
            for (int mt = 0; mt < 4; ++mt)
                af2[mt] = *(const bf16_8*)(&Als[(wm * 64 + mt * 16 + lr) * 32 + q * 8]);
            #pragma unroll
            for (int nt = 0; nt < 4; ++nt)
                bfr[nt] = *(const bf16_8*)(&Bls[(wn * 64 + nt * 16 + lr) * 32 + q * 8]);
            #pragma unroll
            for (int mt = 0; mt < 4; ++mt) {
                #pragma unroll
                for (int nt = 0; nt < 4; ++nt)
                    acc[mt][nt] = __builtin_amdgcn_mfma_f32_16x16x32_bf16(
                        af2[mt], bfr[nt], acc[mt][nt], 0, 0, 0);
            }
            __syncthreads();
        }
    }
    const size_t orow0 = (size_t)chunk * CHUNKD;
    #pragma unroll
    for (int mt = 0; mt < 4; ++mt) {
        #pragma unroll
        for (int nt = 0; nt < 4; ++nt) {
            const int col = n0 + wn * 64 + nt * 16 + lr;
            #pragma unroll
            for (int r = 0; r < 4; ++r) {
                const int row = wm * 64 + mt * 16 + q * 4 + r;
                out[(orow0 + row) * DD + col] = acc[mt][nt][r] * 0.5f;
            }
        }
    }
}

extern "C" void kernel_launch(void* const* d_in, const int* in_sizes, int n_in,
                              void* d_out, int out_size, void* d_ws, size_t ws_size,
                              hipStream_t stream) {
    const float* x   = (const float*)d_in[0];   // [4,4096,1024]
    const float* W   = (const float*)d_in[1];   // [64,1024,1024]
    const float* hyp = (const float*)d_in[2];   // [1024,6]
    float* out = (float*)d_out;

    // ws layout: eidx 1KB | perm 0.5KB @2048 | csum_p 8MB @4096 | A bf16 | WtSw
    const size_t off_eidx = 0;
    const size_t off_perm = 2048;
    const size_t off_csum = 4096;
    const size_t off_a    = off_csum + (size_t)NCHUNK * 8 * DD * 8;
    const size_t off_wt   = off_a + (size_t)NCHUNK * CHUNKD * DD * 2;
    const size_t need     = off_wt + (size_t)ED * DD * DD * 2;

    int* eidx = (int*)((char*)d_ws + off_eidx);
    int* perm = (int*)((char*)d_ws + off_perm);
    __bf16* Abf = (__bf16*)((char*)d_ws + off_a);

    if (ws_size >= need) {
        double* csum_p = (double*)((char*)d_ws + off_csum);
        __bf16* WtSw = (__bf16*)((char*)d_ws + off_wt);
        sum_cvt_kernel<<<NCHUNK * 8, 256, 0, stream>>>(x, Abf, csum_p);
        router2_kernel<<<NCHUNK, 256, 0, stream>>>(csum_p, hyp, eidx);
        wcvt_kernel<<<ED * 16, 256, 0, stream>>>(W, WtSw, eidx, perm);
        ffn_gemm_bf16<<<NCHUNK * 8, 256, 0, stream>>>(Abf, WtSw, eidx, perm, out);
    } else {
        __bf16* Abf2 = (__bf16*)((char*)d_ws + 1024);
        router_kernel<<<NCHUNK, 256, 0, stream>>>(x, hyp, eidx);
        cvt_x_kernel<<<(BD * LD * DD) / (256 * 4), 256, 0, stream>>>(x, Abf2);
        ffn_gemm_fp32w<<<NCHUNK * 8, 256, 0, stream>>>(Abf2, W, eidx, out);
    }
}